// Round 1
// 192.739 us; speedup vs baseline: 1.0971x; 1.0971x over previous
//
#include <hip/hip_runtime.h>

// LocalPathEncoderRobustAdvancedTemporal — R4: 1 sample/block, spill-free GEMM.
// out[b,l,:] = (Σ_f relu(x_f*W1 + b1)) @ W2 + 8*b2   (8x FLOP collapse, exact)
//
// R3 diagnosis: latency-bound at 22% occupancy (MfmaUtil 3.6, VALU 28.8, HBM 28%),
// plus +52MB phantom WRITE_SIZE + VGPR_Count 84 < ~110 live regs => scratch spills.
// R4:
//  * 1 sample/block, grid 2048, 256 thr. GEMM: 4 waves x 32 rows each
//    -> gf[2][4] (32 VGPR) + af (16) + acc[2] (8): fits 128-VGPR cap, no spill.
//  * LDS 45KB -> ~22.5KB: 2 table slots (float4-packed per id) instead of 4.
//    VGPR (not LDS) now sets occupancy: launch_bounds(256,4) => 4+ blocks/CU.
//  * stats/features on thr<128 only (waves 2-3 sleep at barrier, no issue waste).
//  * first-layer g packed as float2 (v_pk_fma_f32) -> ~2x fewer VALU in hot loop.
//  * keeps R2/R3's verified MFMA fragment/store mapping + f2bf RNE numerics.

#define EPSF 1e-6f
#define LDB 136

typedef __attribute__((ext_vector_type(8))) short bf16x8;
typedef __attribute__((ext_vector_type(4))) float f32x4;
typedef __attribute__((ext_vector_type(2))) float f32x2;

__device__ inline short f2bf(float x) {           // fp32 -> bf16 (RNE)
    unsigned u = __float_as_uint(x);
    return (short)((u + 0x7fffu + ((u >> 16) & 1u)) >> 16);
}

__global__ void w2t_prep(const float* __restrict__ W2, short* __restrict__ w2t) {
    const int idx = blockIdx.x * 256 + threadIdx.x;   // 16384
    const int k = idx >> 7, n = idx & 127;
    w2t[n * 128 + k] = f2bf(W2[idx]);
}

template <bool FROMWS>
__launch_bounds__(256, 4)
__global__ void lpe_fused1(const int* __restrict__ src_ids,
                           const int* __restrict__ dst_ids,
                           const int* __restrict__ src_nid,
                           const int* __restrict__ dst_nid,
                           const float* __restrict__ t_now,
                           const float* __restrict__ src_t,
                           const float* __restrict__ dst_t,
                           const float* __restrict__ W1,
                           const float* __restrict__ b1,
                           const float* __restrict__ W2,
                           const float* __restrict__ b2,
                           const short* __restrict__ w2t,
                           float* __restrict__ out)
{
    __shared__ int2  s_idt[128];          // (id, t) per local row
    __shared__ f32x4 s_tab[2][512];       // per (side, id): x=n y=avg z=rec w=last_t
    __shared__ float s_feats[128][9];     // 8 feats, pad to 9 (bank spread)
    __shared__ float s_w1[128], s_b1[128];
    __shared__ short W2T[FROMWS ? 8 : 128 * LDB];   // fallback-only stage

    const int tid = threadIdx.x;
    const int b   = blockIdx.x;           // one sample per block

    // zero the n-component (only field needing init; y/z/w are n>0-guarded)
    #pragma unroll
    for (int u = tid; u < 1024; u += 256) ((float*)s_tab)[u * 4] = 0.f;
    if (tid < 128) { s_w1[tid] = W1[tid]; s_b1[tid] = b1[tid]; }

    const int side = (tid >> 6) & 1;      // valid for tid<128
    const int i    = tid & 63;
    int   my_id = 0;
    float my_t  = 0.f;
    if (tid < 128) {
        const int*   idp = side ? dst_ids : src_ids;
        const float* tp  = side ? dst_t   : src_t;
        my_id = idp[b * 64 + i];
        my_t  = tp [b * 64 + i];
        s_idt[tid] = make_int2(my_id, __float_as_int(my_t));
    }
    if constexpr (!FROMWS) {
        for (int u = tid; u < 16384; u += 256) {
            const int k = u >> 7, n = u & 127;
            W2T[n * LDB + k] = f2bf(W2[u]);
        }
    }
    __syncthreads();

    // ---- single O(L) loop: n, tmax, tmin, rank, has-later (thr<128) ----
    float nf = 0.f, avg = 0.f;
    if (tid < 128) {
        int n = 0, rank = 0, later = 0;
        float tmax = -3.4e38f, tmin = 3.4e38f;
        const int sbase = side * 64;
        #pragma unroll 8
        for (int j = 0; j < 64; ++j) {
            const int2 e = s_idt[sbase + j];
            const float tj = __int_as_float(e.y);
            if (e.x == my_id) {
                ++n;
                tmax = fmaxf(tmax, tj);
                tmin = fminf(tmin, tj);
                if (tj < my_t || (tj == my_t && j < i)) ++rank;
                if (j > i) later = 1;
            }
        }
        nf = (float)n;
        const int split = n >> 1;
        avg = (n > 1) ? (tmax - tmin) / (nf - 1.f) : 0.f;
        if (my_id != 0) {
            s_tab[side][my_id].x = nf;     // benign race: same value from all members
            s_tab[side][my_id].y = avg;
            if (rank == split)             // unique member: sorted(ts)[n//2] == my_t
                s_tab[side][my_id].z = (n >= 4)
                    ? (tmax - my_t) / fmaxf(nf - (float)split - 1.f, 1.f) : 0.f;
            if (!later)                    // unique member: last occurrence
                s_tab[side][my_id].w = my_t;
        }
    }
    __syncthreads();

    // ---- cross features: O(1) table reads (thr<128) ----
    if (tid < 128) {
        const int os = side ^ 1;
        const float rec_m = (my_id != 0) ? s_tab[side][my_id].z : 0.f;
        const f32x4 to = s_tab[os][my_id];
        const float n_o = (my_id != 0) ? to.x : 0.f;
        const bool  hit = n_o > 0.f;
        const float avg_o = hit ? to.y : 0.f;
        const float rec_o = hit ? to.z : 0.f;
        const float lastt = hit ? to.w : 0.f;
        const float cur = t_now[b];
        const int other_node = side ? src_nid[b] : dst_nid[b];
        const float m = (my_id != 0) ? 1.f : 0.f;

        const float rcy_s = cur - my_t;
        const float rcy_o = cur - lastt;
        s_feats[tid][0] = m * nf;
        s_feats[tid][1] = m * n_o;
        s_feats[tid][2] = m * ((my_id == other_node) ? 1.f : 0.f);
        s_feats[tid][3] = m * (hit ? 1.f : 0.f);
        s_feats[tid][4] = m * (hit ? nf / (n_o + EPSF) : 0.f);
        s_feats[tid][5] = m * ((rcy_s > EPSF) ? rcy_o / (rcy_s + EPSF) : 0.f);
        s_feats[tid][6] = m * ((avg_o > EPSF) ? avg / (avg_o + EPSF) : 0.f);
        s_feats[tid][7] = m * ((rec_o > EPSF) ? rec_m / (rec_o + EPSF) : 0.f);
    }
    __syncthreads();

    // ---- GEMM: wave wv owns rows [wv*32, wv*32+32), all 8 e-tiles ----
    const int lane = tid & 63, wv = tid >> 6;
    const int quad = lane >> 4, ln = lane & 15;

    float fxr[2][8];
    #pragma unroll
    for (int rg = 0; rg < 2; ++rg) {
        const int row = wv * 32 + rg * 16 + ln;
        #pragma unroll
        for (int j = 0; j < 8; ++j) fxr[rg][j] = s_feats[row][j];
    }

    bf16x8 gf[2][4];                     // g fragments [row-tile][k-block]
    #pragma unroll
    for (int kk = 0; kk < 4; ++kk) {
        const int kb = kk * 32 + quad * 8;
        #pragma unroll
        for (int rg = 0; rg < 2; ++rg) {
            #pragma unroll
            for (int u2 = 0; u2 < 4; ++u2) {
                const f32x2 w  = *(const f32x2*)&s_w1[kb + u2 * 2];
                const f32x2 bb = *(const f32x2*)&s_b1[kb + u2 * 2];
                f32x2 s = {0.f, 0.f};
                #pragma unroll
                for (int f = 0; f < 8; ++f) {
                    const f32x2 h = w * fxr[rg][f] + bb;      // v_pk_fma_f32
                    s += __builtin_elementwise_max(h, (f32x2){0.f, 0.f});
                }
                gf[rg][kk][u2 * 2]     = f2bf(s.x);
                gf[rg][kk][u2 * 2 + 1] = f2bf(s.y);
            }
        }
    }

    const long side_stride = 2048L * 64L * 128L;
    const long rowbase = (long)b * 64;
    #pragma unroll
    for (int et = 0; et < 8; ++et) {
        bf16x8 af[4];
        #pragma unroll
        for (int kk = 0; kk < 4; ++kk) {
            if constexpr (FROMWS)
                af[kk] = *(const bf16x8*)&w2t[(et * 16 + ln) * 128 + kk * 32 + quad * 8];
            else
                af[kk] = *(const bf16x8*)&W2T[(et * 16 + ln) * LDB + kk * 32 + quad * 8];
        }
        f32x4 acc[2] = {(f32x4){0.f, 0.f, 0.f, 0.f}, (f32x4){0.f, 0.f, 0.f, 0.f}};
        #pragma unroll
        for (int kk = 0; kk < 4; ++kk)
            #pragma unroll
            for (int rg = 0; rg < 2; ++rg)
                acc[rg] = __builtin_amdgcn_mfma_f32_16x16x32_bf16(af[kk], gf[rg][kk], acc[rg], 0, 0, 0);

        const int e0 = et * 16 + quad * 4;
        const f32x4 badd = *(const f32x4*)&b2[e0] * 8.f;
        #pragma unroll
        for (int rg = 0; rg < 2; ++rg) {
            const int row = wv * 32 + rg * 16 + ln;
            const int sd = row >> 6, ii = row & 63;
            *(f32x4*)&out[(long)sd * side_stride + (rowbase + ii) * 128 + e0]
                = acc[rg] + badd;
        }
    }
}

extern "C" void kernel_launch(void* const* d_in, const int* in_sizes, int n_in,
                              void* d_out, int out_size, void* d_ws, size_t ws_size,
                              hipStream_t stream) {
    (void)in_sizes; (void)n_in; (void)out_size;
    const int*   src_ids = (const int*)  d_in[0];
    const int*   dst_ids = (const int*)  d_in[1];
    const int*   src_nid = (const int*)  d_in[2];
    const int*   dst_nid = (const int*)  d_in[3];
    const float* t_now   = (const float*)d_in[4];
    const float* src_t   = (const float*)d_in[5];
    const float* dst_t   = (const float*)d_in[6];
    const float* W1      = (const float*)d_in[7];
    const float* b1      = (const float*)d_in[8];
    const float* W2      = (const float*)d_in[9];
    const float* b2      = (const float*)d_in[10];
    float* out = (float*)d_out;

    if (ws_size >= (size_t)(128 * 128 * 2)) {
        short* w2t = (short*)d_ws;
        w2t_prep<<<64, 256, 0, stream>>>(W2, w2t);
        lpe_fused1<true><<<2048, 256, 0, stream>>>(src_ids, dst_ids, src_nid, dst_nid,
                                                   t_now, src_t, dst_t, W1, b1, W2, b2,
                                                   w2t, out);
    } else {
        lpe_fused1<false><<<2048, 256, 0, stream>>>(src_ids, dst_ids, src_nid, dst_nid,
                                                    t_now, src_t, dst_t, W1, b1, W2, b2,
                                                    nullptr, out);
    }
}